// Round 6
// baseline (1530.484 us; speedup 1.0000x reference)
//
#include <hip/hip_runtime.h>

using bf16   = __bf16;
using bf16x4 = __bf16 __attribute__((ext_vector_type(4)));
using bf16x8 = __bf16 __attribute__((ext_vector_type(8)));
using f32x4  = float  __attribute__((ext_vector_type(4)));

#define NANTHRESH 64

// ---- workspace element offsets (bf16 elements) --------------------------
#define QT_OFF    0LL          // [B*N][C]      2,097,152
#define KT_OFF    2097152LL    // [B*N][4C]     8,388,608
#define V_OFF     10485760LL   // [C][B*N]      2,097,152
#define AWS_OFF   12582912LL   // [B][N][N] attn bf16 copy  8,388,608
#define ATT_OFF   20971520LL   // [B][4][N][N]  33,554,432
#define CW_OFF    54525952LL   // converted weights 992,464
#define FLAG_ELOFF 55518416LL  // int flag
// overlays:
#define CX_OFF    20971520LL   // converted x (ATT region, dead before attn GEMM)
#define DWQ_OFF   23068672LL
#define DWK_OFF   25165824LL
#define DWV_OFF   27262976LL
#define OUTP_OFF  20971520LL   // stage-6 out [B][N][C] (ATT dead after k_midconv)
#define COL_OFF   0LL          // im2col [B][N][2304] (QT..AWS dead after stage6)

__device__ __constant__ int g_nsz[20] = {
    2097152, 2304,256,65536,256, 2304,256,262144,1024,
    2304,256,65536,256, 144, 4,4,4,4, 36, 589824};
__device__ __constant__ long long g_doff[20] = {
    CX_OFF,
    CW_OFF+0,      CW_OFF+2304,   CW_OFF+2560,   CW_OFF+68096,
    CW_OFF+68352,  CW_OFF+70656,  CW_OFF+70912,  CW_OFF+333056,
    CW_OFF+334080, CW_OFF+336384, CW_OFF+336640, CW_OFF+402176,
    CW_OFF+402432, CW_OFF+402576, CW_OFF+402580, CW_OFF+402584,
    CW_OFF+402588, CW_OFF+402592, CW_OFF+402640};

struct SrcPtrs { const void* p[20]; };

__global__ void k_zero(int* p) { if (threadIdx.x < 4) p[threadIdx.x] = 0; }

// fp32 data read as 16-bit halves -> random exponent field -> ~512 hits; bf16 -> 0.
__global__ __launch_bounds__(256) void k_detect(const unsigned short* __restrict__ xs,
                                                int* __restrict__ cnt)
{
    int idx = blockIdx.x * 256 + threadIdx.x;
    int c = 0;
#pragma unroll
    for (int i = 0; i < 16; i++) {
        unsigned short h = xs[idx + i * 16384];
        c += ((h & 0x7F80) == 0x7F80);
    }
    if (c) atomicAdd(cnt, c);
}

__global__ __launch_bounds__(256) void k_convert(SrcPtrs sp, bf16* __restrict__ wsb,
                                                 const int* __restrict__ nf)
{
    const int t = blockIdx.y;
    const int n = g_nsz[t];
    const bool srcf32 = (*nf > NANTHRESH);
    const void* src = sp.p[t];
    bf16* dst = wsb + g_doff[t];
    for (int i = blockIdx.x * 256 + threadIdx.x; i < n; i += 256 * 256) {
        float f = srcf32 ? ((const float*)src)[i] : (float)((const bf16*)src)[i];
        if (!(fabsf(f) < 1e30f)) f = 0.f;
        dst[i] = (bf16)f;
    }
}

// ---------------------------------------------------------------------------
// Canonical NT MFMA GEMM (64x64 tile, BK=64, 16x16x32 bf16 MFMA)
// ---------------------------------------------------------------------------
__global__ __launch_bounds__(256) void gemm_nt(
    const bf16* __restrict__ A, const bf16* __restrict__ Bc,
    const bf16* __restrict__ bias, void* __restrict__ Dv,
    int K, int lda, int ldb, int ldd,
    int zdiv, long long sA1, long long sA2, long long sB1, long long sB2,
    long long sD1, long long sD2, float alpha, int bias_mode,
    const int* __restrict__ nf, int dyn)
{
    const int z  = blockIdx.z;
    const int zq = z / zdiv, zr = z % zdiv;
    A  += (long long)zq * sA1 + (long long)zr * sA2;
    Bc += (long long)zq * sB1 + (long long)zr * sB2;
    const long long zoff = (long long)zq * sD1 + (long long)zr * sD2;
    const bool f32o = dyn && (*nf > NANTHRESH);
    const int m0 = blockIdx.y * 64;
    const int n0 = blockIdx.x * 64;
    __shared__ __align__(16) bf16 As[64 * 72];
    __shared__ __align__(16) bf16 Bs[64 * 72];
    const int tid  = threadIdx.x;
    const int lane = tid & 63;
    const int wave = tid >> 6;
    const int wm   = (wave >> 1) * 32;
    const int wn   = (wave & 1) * 32;
    const int quad = lane >> 4;
    const int l16  = lane & 15;
    f32x4 acc[2][2] = {};
    for (int k0 = 0; k0 < K; k0 += 64) {
#pragma unroll
        for (int i = 0; i < 2; i++) {
            int cid = tid + i * 256;
            int row = cid >> 3;
            int kc  = (cid & 7) * 8;
            *reinterpret_cast<int4*>(&As[row * 72 + kc]) =
                *reinterpret_cast<const int4*>(&A[(long long)(m0 + row) * lda + k0 + kc]);
            *reinterpret_cast<int4*>(&Bs[row * 72 + kc]) =
                *reinterpret_cast<const int4*>(&Bc[(long long)(n0 + row) * ldb + k0 + kc]);
        }
        __syncthreads();
#pragma unroll
        for (int ks = 0; ks < 2; ks++) {
            bf16x8 af[2], bfr[2];
#pragma unroll
            for (int i = 0; i < 2; i++) {
                af[i]  = *reinterpret_cast<const bf16x8*>(&As[(wm + i * 16 + l16) * 72 + ks * 32 + quad * 8]);
                bfr[i] = *reinterpret_cast<const bf16x8*>(&Bs[(wn + i * 16 + l16) * 72 + ks * 32 + quad * 8]);
            }
#pragma unroll
            for (int i = 0; i < 2; i++)
#pragma unroll
                for (int j = 0; j < 2; j++)
                    acc[i][j] = __builtin_amdgcn_mfma_f32_16x16x32_bf16(af[i], bfr[j], acc[i][j], 0, 0, 0);
        }
        __syncthreads();
    }
#pragma unroll
    for (int i = 0; i < 2; i++)
#pragma unroll
        for (int j = 0; j < 2; j++)
#pragma unroll
            for (int r = 0; r < 4; r++) {
                int row = m0 + wm + i * 16 + quad * 4 + r;
                int col = n0 + wn + j * 16 + l16;
                float v = acc[i][j][r] * alpha;
                if (bias_mode == 1) v += (float)bias[row];
                else if (bias_mode == 2) v += (float)bias[col];
                long long idx = zoff + (long long)row * ldd + col;
                if (f32o) ((float*)Dv)[idx] = v;
                else      ((bf16*)Dv)[idx] = (bf16)v;
            }
}

// ---------------------------------------------------------------------------
// Depthwise 3x3 q/k/v fused, coalesced (unchanged)
// ---------------------------------------------------------------------------
__global__ __launch_bounds__(256) void k_dw(
    const bf16* __restrict__ x,
    const bf16* __restrict__ wq, const bf16* __restrict__ bq,
    const bf16* __restrict__ wk, const bf16* __restrict__ bk,
    const bf16* __restrict__ wv, const bf16* __restrict__ bv,
    bf16* __restrict__ dq, bf16* __restrict__ dk, bf16* __restrict__ dv)
{
    __shared__ __align__(16) bf16 obuf[3 * 64 * 72];
    const int ct = blockIdx.x, hp = blockIdx.y, b = blockIdx.z;
    const int c0 = ct * 64, h0 = hp * 2, n0 = hp * 64;
    const int t = threadIdx.x;
    const int c = t & 63, psub = t >> 6;
    const int hl = psub >> 1, wbase = (psub & 1) * 16;
    const int gc = c0 + c;
    const int h = h0 + hl;
    float xr[3][18];
    const bf16* chbase = x + ((long long)b * 256 + gc) * 1024;
#pragma unroll
    for (int r = 0; r < 3; r++) {
        int hr = h + r - 1;
        if (hr >= 0 && hr < 32) {
            const bf16* rp = chbase + hr * 32;
            bf16x8 v0 = *reinterpret_cast<const bf16x8*>(rp + wbase);
            bf16x8 v1 = *reinterpret_cast<const bf16x8*>(rp + wbase + 8);
#pragma unroll
            for (int j = 0; j < 8; j++) { xr[r][1 + j] = (float)v0[j]; xr[r][9 + j] = (float)v1[j]; }
            xr[r][0]  = (wbase > 0)       ? (float)rp[wbase - 1]  : 0.f;
            xr[r][17] = (wbase + 16 < 32) ? (float)rp[wbase + 16] : 0.f;
        } else {
#pragma unroll
            for (int j = 0; j < 18; j++) xr[r][j] = 0.f;
        }
    }
    float wrq[9], wrk[9], wrv[9];
#pragma unroll
    for (int j = 0; j < 9; j++) {
        wrq[j] = (float)wq[gc * 9 + j];
        wrk[j] = (float)wk[gc * 9 + j];
        wrv[j] = (float)wv[gc * 9 + j];
    }
    const float biq = (float)bq[gc], bik = (float)bk[gc], biv = (float)bv[gc];
#pragma unroll
    for (int i = 0; i < 16; i++) {
        float aq = biq, ak = bik, av = biv;
#pragma unroll
        for (int r = 0; r < 3; r++)
#pragma unroll
            for (int d = 0; d < 3; d++) {
                float xv = xr[r][i + d];
                aq += xv * wrq[r * 3 + d];
                ak += xv * wrk[r * 3 + d];
                av += xv * wrv[r * 3 + d];
            }
        int p = hl * 32 + wbase + i;
        obuf[0 * 4608 + p * 72 + c] = (bf16)aq;
        obuf[1 * 4608 + p * 72 + c] = (bf16)ak;
        obuf[2 * 4608 + p * 72 + c] = (bf16)av;
    }
    __syncthreads();
    bf16* dsts[3] = {dq, dk, dv};
    const int chunk = t & 7, pr0 = t >> 3;
#pragma unroll
    for (int t3 = 0; t3 < 3; t3++) {
        bf16* dst = dsts[t3];
#pragma unroll
        for (int rep = 0; rep < 2; rep++) {
            int pr = pr0 + rep * 32;
            int4 val = *reinterpret_cast<const int4*>(&obuf[t3 * 4608 + pr * 72 + chunk * 8]);
            *reinterpret_cast<int4*>(&dst[((long long)b * 1024 + n0 + pr) * 256 + c0 + chunk * 8]) = val;
        }
    }
}

// ---------------------------------------------------------------------------
// FUSED middle v2: conv3x3(4->4)+BN -> x*softmax(x) -> conv3x3(4->1).
// Gated mid rows stay in REGISTERS; conv1 m-halo via __shfl + 768B LDS wave
// edges. LDS ~14KB (was 62KB) -> 4 blocks/CU; bank-conflict-free.
// ---------------------------------------------------------------------------
__global__ __launch_bounds__(256, 4) void k_midconv(
    const bf16* __restrict__ att,   // [B][4][N][N]
    const bf16* __restrict__ w0,
    const bf16* __restrict__ gamma, const bf16* __restrict__ beta,
    const bf16* __restrict__ mean,  const bf16* __restrict__ var,
    const bf16* __restrict__ w1,
    bf16* __restrict__ aws,         // [B][N][N]
    void* __restrict__ dout, const int* __restrict__ nf)
{
    __shared__ __align__(16) bf16 pm[24 * 256];    // reduction partials 12KB
    __shared__ float w0ld[144];                    // [c][r][k*3+d]
    __shared__ float w1s[36];
    __shared__ float mxs[24], rsum[24];
    __shared__ float sEL[4][24], sER[4][24];       // cross-wave halo edges

    const int rt = blockIdx.x, b = blockIdx.y;
    const int n0 = rt * 4;
    const int tid = threadIdx.x;
    const int m0 = tid * 4;
    const int wv_ = tid >> 6, lane = tid & 63;

    if (tid < 144) {
        int c = tid / 36, rem = tid % 36, r = rem / 12, kd = rem % 12;
        int k = kd / 3, d = kd % 3;
        w0ld[(c * 3 + r) * 12 + kd] = (float)w0[((k * 4 + c) * 3 + r) * 3 + d];
    } else if (tid < 180) {
        w1s[tid - 144] = (float)w1[tid - 144];
    }
    float bns[4], bnb[4];
#pragma unroll
    for (int k = 0; k < 4; k++) {
        float inv = rsqrtf((float)var[k] + 1e-5f);
        bns[k] = (float)gamma[k] * inv;
        bnb[k] = (float)beta[k] - (float)mean[k] * bns[k];
    }
    __syncthreads();

    // ---- mid conv: vals[j][k][u] (mid row nm=n0-1+j), one halo row live ----
    float vals[6][4][4] = {};
    const bf16* attb = att + (long long)b * 4194304;
    for (int c = 0; c < 4; c++) {
#pragma unroll
        for (int rw = 0; rw < 8; rw++) {
            int row = n0 - 2 + rw;
            float rv6[6];
            if (row >= 0 && row < 1024) {
                const bf16* rp = attb + ((long long)c * 1024 + row) * 1024;
                bf16x4 t4 = *reinterpret_cast<const bf16x4*>(rp + m0);
#pragma unroll
                for (int u = 0; u < 4; u++) rv6[1 + u] = (float)t4[u];
                rv6[0] = (m0 > 0)        ? (float)rp[m0 - 1] : 0.f;
                rv6[5] = (m0 + 4 < 1024) ? (float)rp[m0 + 4] : 0.f;
            } else {
#pragma unroll
                for (int u = 0; u < 6; u++) rv6[u] = 0.f;
            }
            // rows j with j + r == rw, r in [0,3)
#pragma unroll
            for (int r = 0; r < 3; r++) {
                int j = rw - r;
                if (j < 0 || j > 5) continue;
#pragma unroll
                for (int k = 0; k < 4; k++)
#pragma unroll
                    for (int d = 0; d < 3; d++)
#pragma unroll
                        for (int u = 0; u < 4; u++)
                            vals[j][k][u] += w0ld[(c * 3 + r) * 12 + k * 3 + d] * rv6[u + d];
            }
        }
    }
    // BN
#pragma unroll
    for (int j = 0; j < 6; j++)
#pragma unroll
        for (int k = 0; k < 4; k++)
#pragma unroll
            for (int u = 0; u < 4; u++)
                vals[j][k][u] = vals[j][k][u] * bns[k] + bnb[k];

    // ---- softmax over m per (k,j) row: rid = k*6+j ----
#pragma unroll
    for (int j = 0; j < 6; j++)
#pragma unroll
        for (int k = 0; k < 4; k++) {
            float lm = fmaxf(fmaxf(vals[j][k][0], vals[j][k][1]),
                             fmaxf(vals[j][k][2], vals[j][k][3]));
            pm[(k * 6 + j) * 256 + tid] = (bf16)lm;
        }
    __syncthreads();
#pragma unroll
    for (int s = 0; s < 6; s++) {
        int rid = wv_ * 6 + s;
        bf16x4 p = *reinterpret_cast<const bf16x4*>(&pm[rid * 256 + lane * 4]);
        float mx = fmaxf(fmaxf((float)p[0], (float)p[1]), fmaxf((float)p[2], (float)p[3]));
#pragma unroll
        for (int off = 32; off; off >>= 1) mx = fmaxf(mx, __shfl_xor(mx, off));
        if (lane == 0) mxs[rid] = mx;
    }
    __syncthreads();
#pragma unroll
    for (int j = 0; j < 6; j++)
#pragma unroll
        for (int k = 0; k < 4; k++) {
            int rid = k * 6 + j;
            float mx = mxs[rid];
            float ls = 0.f;
#pragma unroll
            for (int u = 0; u < 4; u++) ls += __expf(vals[j][k][u] - mx);
            pm[rid * 256 + tid] = (bf16)ls;
        }
    __syncthreads();
#pragma unroll
    for (int s = 0; s < 6; s++) {
        int rid = wv_ * 6 + s;
        bf16x4 p = *reinterpret_cast<const bf16x4*>(&pm[rid * 256 + lane * 4]);
        float sm = (float)p[0] + (float)p[1] + (float)p[2] + (float)p[3];
#pragma unroll
        for (int off = 32; off; off >>= 1) sm += __shfl_xor(sm, off);
        if (lane == 0) rsum[rid] = sm;
    }
    __syncthreads();

    // ---- gate in registers; zero invalid rows ----
#pragma unroll
    for (int j = 0; j < 6; j++) {
        int nm = n0 - 1 + j;
        bool valid = (nm >= 0 && nm < 1024);
#pragma unroll
        for (int k = 0; k < 4; k++) {
            int rid = k * 6 + j;
            float mx = mxs[rid], ri = 1.0f / rsum[rid];
#pragma unroll
            for (int u = 0; u < 4; u++) {
                float t = vals[j][k][u];
                vals[j][k][u] = valid ? (t * __expf(t - mx) * ri) : 0.f;
            }
        }
    }

    // ---- cross-wave halo edges ----
    if (lane == 63 && wv_ < 3) {
#pragma unroll
        for (int j = 0; j < 6; j++)
#pragma unroll
            for (int k = 0; k < 4; k++)
                sEL[wv_ + 1][k * 6 + j] = vals[j][k][3];
    }
    if (lane == 0 && wv_ > 0) {
#pragma unroll
        for (int j = 0; j < 6; j++)
#pragma unroll
            for (int k = 0; k < 4; k++)
                sER[wv_ - 1][k * 6 + j] = vals[j][k][0];
    }
    __syncthreads();

    // ---- conv1 (4->1): registers + shfl halo ----
    float acc1[4][4] = {};
#pragma unroll
    for (int k = 0; k < 4; k++)
#pragma unroll
        for (int j = 0; j < 6; j++) {
            int rid = k * 6 + j;
            float left  = __shfl_up(vals[j][k][3], 1);
            float right = __shfl_down(vals[j][k][0], 1);
            if (lane == 0)  left  = (wv_ > 0) ? sEL[wv_][rid] : 0.f;
            if (lane == 63) right = (wv_ < 3) ? sER[wv_][rid] : 0.f;
            float vec[6] = {left, vals[j][k][0], vals[j][k][1],
                            vals[j][k][2], vals[j][k][3], right};
#pragma unroll
            for (int i = 0; i < 4; i++) {
                int r = j - i;
                if (r < 0 || r > 2) continue;
#pragma unroll
                for (int d = 0; d < 3; d++) {
                    float wv1 = w1s[(k * 3 + r) * 3 + d];
#pragma unroll
                    for (int u = 0; u < 4; u++)
                        acc1[i][u] += wv1 * vec[u + d];
                }
            }
        }

    // ---- write aws (bf16) + final out1 (flag dtype) ----
    const bool f32o = (*nf > NANTHRESH);
    bf16* awsb = aws + (long long)b * 1048576;
#pragma unroll
    for (int i = 0; i < 4; i++) {
        int n = n0 + i;
        bf16x4 o4;
#pragma unroll
        for (int u = 0; u < 4; u++) o4[u] = (bf16)acc1[i][u];
        *reinterpret_cast<bf16x4*>(&awsb[(long long)n * 1024 + m0]) = o4;
        long long fo = 2097152LL + (long long)b * 1048576 + (long long)n * 1024 + m0;
        if (f32o) {
            f32x4 of = {acc1[i][0], acc1[i][1], acc1[i][2], acc1[i][3]};
            *reinterpret_cast<f32x4*>(&((float*)dout)[fo]) = of;
        } else {
            *reinterpret_cast<bf16x4*>(&((bf16*)dout)[fo]) = o4;
        }
    }
}

// ---------------------------------------------------------------------------
// im2col: src [B][N][C] -> dst [B][N][C*9] (k = ci*9 + t)
// ---------------------------------------------------------------------------
__global__ __launch_bounds__(256) void k_im2col(
    const bf16* __restrict__ src, bf16* __restrict__ dst)
{
    const int blk = blockIdx.x;
    const int b = blk >> 10, n = blk & 1023;
    const int h = n >> 5, w = n & 31;
    const int ci = threadIdx.x;
    const bf16* sb = src + (long long)b * 262144;
    bf16* db = dst + ((long long)b * 1024 + n) * 2304 + ci * 9;
#pragma unroll
    for (int dh = 0; dh < 3; dh++)
#pragma unroll
        for (int dw_ = 0; dw_ < 3; dw_++) {
            int hh = h + dh - 1, ww = w + dw_ - 1;
            bf16 vv = (bf16)0.0f;
            if (hh >= 0 && hh < 32 && ww >= 0 && ww < 32)
                vv = sb[(hh * 32 + ww) * 256 + ci];
            db[dh * 3 + dw_] = vv;
        }
}

extern "C" void kernel_launch(void* const* d_in, const int* in_sizes, int n_in,
                              void* d_out, int out_size, void* d_ws, size_t ws_size,
                              hipStream_t stream)
{
    bf16* ws = (bf16*)d_ws;
    int* flagp = (int*)(ws + FLAG_ELOFF);

    bf16* cw      = ws + CW_OFF;
    bf16* cx      = ws + CX_OFF;
    bf16* dwq     = ws + DWQ_OFF;
    bf16* dwk     = ws + DWK_OFF;
    bf16* dwv     = ws + DWV_OFF;
    bf16* qT      = ws + QT_OFF;
    bf16* kT      = ws + KT_OFF;
    bf16* v       = ws + V_OFF;
    bf16* aws     = ws + AWS_OFF;
    bf16* att     = ws + ATT_OFF;
    bf16* outp    = ws + OUTP_OFF;
    bf16* colbuf  = ws + COL_OFF;

    bf16* c_qa_dw_w = cw + 0;      bf16* c_qa_dw_b = cw + 2304;
    bf16* c_qa_pw_w = cw + 2560;   bf16* c_qa_pw_b = cw + 68096;
    bf16* c_ka_dw_w = cw + 68352;  bf16* c_ka_dw_b = cw + 70656;
    bf16* c_ka_pw_w = cw + 70912;  bf16* c_ka_pw_b = cw + 333056;
    bf16* c_va_dw_w = cw + 334080; bf16* c_va_dw_b = cw + 336384;
    bf16* c_va_pw_w = cw + 336640; bf16* c_va_pw_b = cw + 402176;
    bf16* c_attn0   = cw + 402432;
    bf16* c_bn_g    = cw + 402576; bf16* c_bn_b = cw + 402580;
    bf16* c_bn_m    = cw + 402584; bf16* c_bn_v = cw + 402588;
    bf16* c_attn1   = cw + 402592;
    bf16* c_proj    = cw + 402640;

    // 0) dtype detect + normalize inputs to bf16
    k_zero<<<1, 64, 0, stream>>>(flagp);
    k_detect<<<64, 256, 0, stream>>>((const unsigned short*)d_in[0], flagp);
    SrcPtrs sp;
    for (int i = 0; i < 20; i++) sp.p[i] = d_in[i];
    k_convert<<<dim3(256, 20), 256, 0, stream>>>(sp, ws, flagp);

    // 1) depthwise convs (transposed outputs)
    k_dw<<<dim3(4, 16, 8), 256, 0, stream>>>(cx, c_qa_dw_w, c_qa_dw_b, c_ka_dw_w, c_ka_dw_b,
                                             c_va_dw_w, c_va_dw_b, dwq, dwk, dwv);
    // 2) pointwise GEMMs
    gemm_nt<<<dim3(4, 128, 1), 256, 0, stream>>>(dwq, c_qa_pw_w, c_qa_pw_b, qT,
        256, 256, 256, 256, 1, 0, 0, 0, 0, 0, 0, 1.0f, 2, flagp, 0);
    gemm_nt<<<dim3(16, 128, 1), 256, 0, stream>>>(dwk, c_ka_pw_w, c_ka_pw_b, kT,
        256, 256, 256, 1024, 1, 0, 0, 0, 0, 0, 0, 1.0f, 2, flagp, 0);
    gemm_nt<<<dim3(128, 4, 1), 256, 0, stream>>>(c_va_pw_w, dwv, c_va_pw_b, v,
        256, 256, 256, 8192, 1, 0, 0, 0, 0, 0, 0, 1.0f, 1, flagp, 0);
    // 3) attn = scale * q^T k, full batch: z = b*4+kk
    gemm_nt<<<dim3(16, 16, 32), 256, 0, stream>>>(qT, kT, nullptr, att,
        256, 256, 1024, 1024,
        4, 262144LL, 0LL, 1048576LL, 256LL, 4194304LL, 1048576LL,
        0.0625f, 0, flagp, 0);
    // 4+5) fused conv4->4 + BN + gating + conv4->1  -> aws + out1
    k_midconv<<<dim3(256, 8), 256, 0, stream>>>(att, c_attn0, c_bn_g, c_bn_b, c_bn_m, c_bn_v,
                                                c_attn1, aws, d_out, flagp);
    // 6) outp[b][n][c] = sum_m aws[b][n][m] * v[c][b*1024+m]
    gemm_nt<<<dim3(4, 16, 8), 256, 0, stream>>>(aws, v, nullptr, outp,
        1024, 1024, 8192, 256,
        1, 1048576LL, 0LL, 1024LL, 0LL, 262144LL, 0LL, 1.0f, 0, flagp, 0);
    // 7) proj conv: im2col + GEMM -> out0 (flag dtype)
    k_im2col<<<8192, 256, 0, stream>>>(outp, colbuf);
    gemm_nt<<<dim3(16, 4, 8), 256, 0, stream>>>(c_proj, colbuf, nullptr, d_out,
        2304, 2304, 2304, 1024,
        1, 0LL, 0LL, 2359296LL, 0LL, 262144LL, 0LL, 1.0f, 0, flagp, 1);
}

// Round 7
// 507.061 us; speedup vs baseline: 3.0183x; 3.0183x over previous
//
#include <hip/hip_runtime.h>

using bf16   = __bf16;
using bf16x4 = __bf16 __attribute__((ext_vector_type(4)));
using bf16x8 = __bf16 __attribute__((ext_vector_type(8)));
using f32x4  = float  __attribute__((ext_vector_type(4)));

#define NANTHRESH 64

// ---- workspace element offsets (bf16 elements) --------------------------
#define QT_OFF    0LL          // [B*N][C]      2,097,152
#define KT_OFF    2097152LL    // [B*N][4C]     8,388,608
#define V_OFF     10485760LL   // [C][B*N]      2,097,152
#define AWS_OFF   12582912LL   // [B][N][N] attn bf16 copy  8,388,608
#define ATT_OFF   20971520LL   // [B][4][N][N]  33,554,432
#define CW_OFF    54525952LL   // converted weights 992,464
#define FLAG_ELOFF 55518416LL  // int flag
// overlays:
#define CX_OFF    20971520LL   // converted x (ATT region, dead before attn GEMM)
#define DWQ_OFF   23068672LL
#define DWK_OFF   25165824LL
#define DWV_OFF   27262976LL
#define OUTP_OFF  20971520LL   // stage-6 out [B][N][C] (ATT dead after k_midconv)
#define COL_OFF   0LL          // im2col [B][N][2304] (QT..AWS dead after stage6)

__device__ __constant__ int g_nsz[20] = {
    2097152, 2304,256,65536,256, 2304,256,262144,1024,
    2304,256,65536,256, 144, 4,4,4,4, 36, 589824};
__device__ __constant__ long long g_doff[20] = {
    CX_OFF,
    CW_OFF+0,      CW_OFF+2304,   CW_OFF+2560,   CW_OFF+68096,
    CW_OFF+68352,  CW_OFF+70656,  CW_OFF+70912,  CW_OFF+333056,
    CW_OFF+334080, CW_OFF+336384, CW_OFF+336640, CW_OFF+402176,
    CW_OFF+402432, CW_OFF+402576, CW_OFF+402580, CW_OFF+402584,
    CW_OFF+402588, CW_OFF+402592, CW_OFF+402640};

struct SrcPtrs { const void* p[20]; };

__global__ void k_zero(int* p) { if (threadIdx.x < 4) p[threadIdx.x] = 0; }

// fp32 data read as 16-bit halves -> random exponent field -> ~512 hits; bf16 -> 0.
__global__ __launch_bounds__(256) void k_detect(const unsigned short* __restrict__ xs,
                                                int* __restrict__ cnt)
{
    int idx = blockIdx.x * 256 + threadIdx.x;
    int c = 0;
#pragma unroll
    for (int i = 0; i < 16; i++) {
        unsigned short h = xs[idx + i * 16384];
        c += ((h & 0x7F80) == 0x7F80);
    }
    if (c) atomicAdd(cnt, c);
}

__global__ __launch_bounds__(256) void k_convert(SrcPtrs sp, bf16* __restrict__ wsb,
                                                 const int* __restrict__ nf)
{
    const int t = blockIdx.y;
    const int n = g_nsz[t];
    const bool srcf32 = (*nf > NANTHRESH);
    const void* src = sp.p[t];
    bf16* dst = wsb + g_doff[t];
    for (int i = blockIdx.x * 256 + threadIdx.x; i < n; i += 256 * 256) {
        float f = srcf32 ? ((const float*)src)[i] : (float)((const bf16*)src)[i];
        if (!(fabsf(f) < 1e30f)) f = 0.f;
        dst[i] = (bf16)f;
    }
}

// ---------------------------------------------------------------------------
// Canonical NT MFMA GEMM (64x64 tile, BK=64, 16x16x32 bf16 MFMA)
// ---------------------------------------------------------------------------
__global__ __launch_bounds__(256) void gemm_nt(
    const bf16* __restrict__ A, const bf16* __restrict__ Bc,
    const bf16* __restrict__ bias, void* __restrict__ Dv,
    int K, int lda, int ldb, int ldd,
    int zdiv, long long sA1, long long sA2, long long sB1, long long sB2,
    long long sD1, long long sD2, float alpha, int bias_mode,
    const int* __restrict__ nf, int dyn)
{
    const int z  = blockIdx.z;
    const int zq = z / zdiv, zr = z % zdiv;
    A  += (long long)zq * sA1 + (long long)zr * sA2;
    Bc += (long long)zq * sB1 + (long long)zr * sB2;
    const long long zoff = (long long)zq * sD1 + (long long)zr * sD2;
    const bool f32o = dyn && (*nf > NANTHRESH);
    const int m0 = blockIdx.y * 64;
    const int n0 = blockIdx.x * 64;
    __shared__ __align__(16) bf16 As[64 * 72];
    __shared__ __align__(16) bf16 Bs[64 * 72];
    const int tid  = threadIdx.x;
    const int lane = tid & 63;
    const int wave = tid >> 6;
    const int wm   = (wave >> 1) * 32;
    const int wn   = (wave & 1) * 32;
    const int quad = lane >> 4;
    const int l16  = lane & 15;
    f32x4 acc[2][2] = {};
    for (int k0 = 0; k0 < K; k0 += 64) {
#pragma unroll
        for (int i = 0; i < 2; i++) {
            int cid = tid + i * 256;
            int row = cid >> 3;
            int kc  = (cid & 7) * 8;
            *reinterpret_cast<int4*>(&As[row * 72 + kc]) =
                *reinterpret_cast<const int4*>(&A[(long long)(m0 + row) * lda + k0 + kc]);
            *reinterpret_cast<int4*>(&Bs[row * 72 + kc]) =
                *reinterpret_cast<const int4*>(&Bc[(long long)(n0 + row) * ldb + k0 + kc]);
        }
        __syncthreads();
#pragma unroll
        for (int ks = 0; ks < 2; ks++) {
            bf16x8 af[2], bfr[2];
#pragma unroll
            for (int i = 0; i < 2; i++) {
                af[i]  = *reinterpret_cast<const bf16x8*>(&As[(wm + i * 16 + l16) * 72 + ks * 32 + quad * 8]);
                bfr[i] = *reinterpret_cast<const bf16x8*>(&Bs[(wn + i * 16 + l16) * 72 + ks * 32 + quad * 8]);
            }
#pragma unroll
            for (int i = 0; i < 2; i++)
#pragma unroll
                for (int j = 0; j < 2; j++)
                    acc[i][j] = __builtin_amdgcn_mfma_f32_16x16x32_bf16(af[i], bfr[j], acc[i][j], 0, 0, 0);
        }
        __syncthreads();
    }
#pragma unroll
    for (int i = 0; i < 2; i++)
#pragma unroll
        for (int j = 0; j < 2; j++)
#pragma unroll
            for (int r = 0; r < 4; r++) {
                int row = m0 + wm + i * 16 + quad * 4 + r;
                int col = n0 + wn + j * 16 + l16;
                float v = acc[i][j][r] * alpha;
                if (bias_mode == 1) v += (float)bias[row];
                else if (bias_mode == 2) v += (float)bias[col];
                long long idx = zoff + (long long)row * ldd + col;
                if (f32o) ((float*)Dv)[idx] = v;
                else      ((bf16*)Dv)[idx] = (bf16)v;
            }
}

// ---------------------------------------------------------------------------
// Depthwise 3x3 q/k/v fused, coalesced (unchanged)
// ---------------------------------------------------------------------------
__global__ __launch_bounds__(256) void k_dw(
    const bf16* __restrict__ x,
    const bf16* __restrict__ wq, const bf16* __restrict__ bq,
    const bf16* __restrict__ wk, const bf16* __restrict__ bk,
    const bf16* __restrict__ wv, const bf16* __restrict__ bv,
    bf16* __restrict__ dq, bf16* __restrict__ dk, bf16* __restrict__ dv)
{
    __shared__ __align__(16) bf16 obuf[3 * 64 * 72];
    const int ct = blockIdx.x, hp = blockIdx.y, b = blockIdx.z;
    const int c0 = ct * 64, h0 = hp * 2, n0 = hp * 64;
    const int t = threadIdx.x;
    const int c = t & 63, psub = t >> 6;
    const int hl = psub >> 1, wbase = (psub & 1) * 16;
    const int gc = c0 + c;
    const int h = h0 + hl;
    float xr[3][18];
    const bf16* chbase = x + ((long long)b * 256 + gc) * 1024;
#pragma unroll
    for (int r = 0; r < 3; r++) {
        int hr = h + r - 1;
        if (hr >= 0 && hr < 32) {
            const bf16* rp = chbase + hr * 32;
            bf16x8 v0 = *reinterpret_cast<const bf16x8*>(rp + wbase);
            bf16x8 v1 = *reinterpret_cast<const bf16x8*>(rp + wbase + 8);
#pragma unroll
            for (int j = 0; j < 8; j++) { xr[r][1 + j] = (float)v0[j]; xr[r][9 + j] = (float)v1[j]; }
            xr[r][0]  = (wbase > 0)       ? (float)rp[wbase - 1]  : 0.f;
            xr[r][17] = (wbase + 16 < 32) ? (float)rp[wbase + 16] : 0.f;
        } else {
#pragma unroll
            for (int j = 0; j < 18; j++) xr[r][j] = 0.f;
        }
    }
    float wrq[9], wrk[9], wrv[9];
#pragma unroll
    for (int j = 0; j < 9; j++) {
        wrq[j] = (float)wq[gc * 9 + j];
        wrk[j] = (float)wk[gc * 9 + j];
        wrv[j] = (float)wv[gc * 9 + j];
    }
    const float biq = (float)bq[gc], bik = (float)bk[gc], biv = (float)bv[gc];
#pragma unroll
    for (int i = 0; i < 16; i++) {
        float aq = biq, ak = bik, av = biv;
#pragma unroll
        for (int r = 0; r < 3; r++)
#pragma unroll
            for (int d = 0; d < 3; d++) {
                float xv = xr[r][i + d];
                aq += xv * wrq[r * 3 + d];
                ak += xv * wrk[r * 3 + d];
                av += xv * wrv[r * 3 + d];
            }
        int p = hl * 32 + wbase + i;
        obuf[0 * 4608 + p * 72 + c] = (bf16)aq;
        obuf[1 * 4608 + p * 72 + c] = (bf16)ak;
        obuf[2 * 4608 + p * 72 + c] = (bf16)av;
    }
    __syncthreads();
    bf16* dsts[3] = {dq, dk, dv};
    const int chunk = t & 7, pr0 = t >> 3;
#pragma unroll
    for (int t3 = 0; t3 < 3; t3++) {
        bf16* dst = dsts[t3];
#pragma unroll
        for (int rep = 0; rep < 2; rep++) {
            int pr = pr0 + rep * 32;
            int4 val = *reinterpret_cast<const int4*>(&obuf[t3 * 4608 + pr * 72 + chunk * 8]);
            *reinterpret_cast<int4*>(&dst[((long long)b * 1024 + n0 + pr) * 256 + c0 + chunk * 8]) = val;
        }
    }
}

// ---------------------------------------------------------------------------
// FUSED middle v2b: conv3x3(4->4)+BN -> x*softmax(x) -> conv3x3(4->1).
// Register-resident gating + shfl halo. NOTE: no waves-per-EU bound — the
// kernel needs ~110-130 live VGPRs; forcing 4 waves/SIMD (round 6) made the
// allocator pick 64 VGPRs and spill ~4 GB to scratch (FETCH 65MB->1.5GB).
// ---------------------------------------------------------------------------
__global__ __launch_bounds__(256) void k_midconv(
    const bf16* __restrict__ att,   // [B][4][N][N]
    const bf16* __restrict__ w0,
    const bf16* __restrict__ gamma, const bf16* __restrict__ beta,
    const bf16* __restrict__ mean,  const bf16* __restrict__ var,
    const bf16* __restrict__ w1,
    bf16* __restrict__ aws,         // [B][N][N]
    void* __restrict__ dout, const int* __restrict__ nf)
{
    __shared__ __align__(16) bf16 pm[24 * 256];    // reduction partials 12KB
    __shared__ float w0ld[144];                    // [c][r][k*3+d]
    __shared__ float w1s[36];
    __shared__ float mxs[24], rsum[24];
    __shared__ float sEL[4][24], sER[4][24];       // cross-wave halo edges

    const int rt = blockIdx.x, b = blockIdx.y;
    const int n0 = rt * 4;
    const int tid = threadIdx.x;
    const int m0 = tid * 4;
    const int wv_ = tid >> 6, lane = tid & 63;

    if (tid < 144) {
        int c = tid / 36, rem = tid % 36, r = rem / 12, kd = rem % 12;
        int k = kd / 3, d = kd % 3;
        w0ld[(c * 3 + r) * 12 + kd] = (float)w0[((k * 4 + c) * 3 + r) * 3 + d];
    } else if (tid < 180) {
        w1s[tid - 144] = (float)w1[tid - 144];
    }
    float bns[4], bnb[4];
#pragma unroll
    for (int k = 0; k < 4; k++) {
        float inv = rsqrtf((float)var[k] + 1e-5f);
        bns[k] = (float)gamma[k] * inv;
        bnb[k] = (float)beta[k] - (float)mean[k] * bns[k];
    }
    __syncthreads();

    // ---- mid conv: vals[j][k][u] (mid row nm=n0-1+j), one halo row live ----
    float vals[6][4][4] = {};
    const bf16* attb = att + (long long)b * 4194304;
    for (int c = 0; c < 4; c++) {
#pragma unroll
        for (int rw = 0; rw < 8; rw++) {
            int row = n0 - 2 + rw;
            float rv6[6];
            if (row >= 0 && row < 1024) {
                const bf16* rp = attb + ((long long)c * 1024 + row) * 1024;
                bf16x4 t4 = *reinterpret_cast<const bf16x4*>(rp + m0);
#pragma unroll
                for (int u = 0; u < 4; u++) rv6[1 + u] = (float)t4[u];
                rv6[0] = (m0 > 0)        ? (float)rp[m0 - 1] : 0.f;
                rv6[5] = (m0 + 4 < 1024) ? (float)rp[m0 + 4] : 0.f;
            } else {
#pragma unroll
                for (int u = 0; u < 6; u++) rv6[u] = 0.f;
            }
            // rows j with j + r == rw, r in [0,3)
#pragma unroll
            for (int r = 0; r < 3; r++) {
                int j = rw - r;
                if (j < 0 || j > 5) continue;
#pragma unroll
                for (int k = 0; k < 4; k++)
#pragma unroll
                    for (int d = 0; d < 3; d++)
#pragma unroll
                        for (int u = 0; u < 4; u++)
                            vals[j][k][u] += w0ld[(c * 3 + r) * 12 + k * 3 + d] * rv6[u + d];
            }
        }
    }
    // BN
#pragma unroll
    for (int j = 0; j < 6; j++)
#pragma unroll
        for (int k = 0; k < 4; k++)
#pragma unroll
            for (int u = 0; u < 4; u++)
                vals[j][k][u] = vals[j][k][u] * bns[k] + bnb[k];

    // ---- softmax over m per (k,j) row: rid = k*6+j ----
#pragma unroll
    for (int j = 0; j < 6; j++)
#pragma unroll
        for (int k = 0; k < 4; k++) {
            float lm = fmaxf(fmaxf(vals[j][k][0], vals[j][k][1]),
                             fmaxf(vals[j][k][2], vals[j][k][3]));
            pm[(k * 6 + j) * 256 + tid] = (bf16)lm;
        }
    __syncthreads();
#pragma unroll
    for (int s = 0; s < 6; s++) {
        int rid = wv_ * 6 + s;
        bf16x4 p = *reinterpret_cast<const bf16x4*>(&pm[rid * 256 + lane * 4]);
        float mx = fmaxf(fmaxf((float)p[0], (float)p[1]), fmaxf((float)p[2], (float)p[3]));
#pragma unroll
        for (int off = 32; off; off >>= 1) mx = fmaxf(mx, __shfl_xor(mx, off));
        if (lane == 0) mxs[rid] = mx;
    }
    __syncthreads();
#pragma unroll
    for (int j = 0; j < 6; j++)
#pragma unroll
        for (int k = 0; k < 4; k++) {
            int rid = k * 6 + j;
            float mx = mxs[rid];
            float ls = 0.f;
#pragma unroll
            for (int u = 0; u < 4; u++) ls += __expf(vals[j][k][u] - mx);
            pm[rid * 256 + tid] = (bf16)ls;
        }
    __syncthreads();
#pragma unroll
    for (int s = 0; s < 6; s++) {
        int rid = wv_ * 6 + s;
        bf16x4 p = *reinterpret_cast<const bf16x4*>(&pm[rid * 256 + lane * 4]);
        float sm = (float)p[0] + (float)p[1] + (float)p[2] + (float)p[3];
#pragma unroll
        for (int off = 32; off; off >>= 1) sm += __shfl_xor(sm, off);
        if (lane == 0) rsum[rid] = sm;
    }
    __syncthreads();

    // ---- gate in registers; zero invalid rows ----
#pragma unroll
    for (int j = 0; j < 6; j++) {
        int nm = n0 - 1 + j;
        bool valid = (nm >= 0 && nm < 1024);
#pragma unroll
        for (int k = 0; k < 4; k++) {
            int rid = k * 6 + j;
            float mx = mxs[rid], ri = 1.0f / rsum[rid];
#pragma unroll
            for (int u = 0; u < 4; u++) {
                float t = vals[j][k][u];
                vals[j][k][u] = valid ? (t * __expf(t - mx) * ri) : 0.f;
            }
        }
    }

    // ---- cross-wave halo edges ----
    if (lane == 63 && wv_ < 3) {
#pragma unroll
        for (int j = 0; j < 6; j++)
#pragma unroll
            for (int k = 0; k < 4; k++)
                sEL[wv_ + 1][k * 6 + j] = vals[j][k][3];
    }
    if (lane == 0 && wv_ > 0) {
#pragma unroll
        for (int j = 0; j < 6; j++)
#pragma unroll
            for (int k = 0; k < 4; k++)
                sER[wv_ - 1][k * 6 + j] = vals[j][k][0];
    }
    __syncthreads();

    // ---- conv1 (4->1): registers + shfl halo ----
    float acc1[4][4] = {};
#pragma unroll
    for (int k = 0; k < 4; k++)
#pragma unroll
        for (int j = 0; j < 6; j++) {
            int rid = k * 6 + j;
            float left  = __shfl_up(vals[j][k][3], 1);
            float right = __shfl_down(vals[j][k][0], 1);
            if (lane == 0)  left  = (wv_ > 0) ? sEL[wv_][rid] : 0.f;
            if (lane == 63) right = (wv_ < 3) ? sER[wv_][rid] : 0.f;
            float vec[6] = {left, vals[j][k][0], vals[j][k][1],
                            vals[j][k][2], vals[j][k][3], right};
#pragma unroll
            for (int i = 0; i < 4; i++) {
                int r = j - i;
                if (r < 0 || r > 2) continue;
#pragma unroll
                for (int d = 0; d < 3; d++) {
                    float wv1 = w1s[(k * 3 + r) * 3 + d];
#pragma unroll
                    for (int u = 0; u < 4; u++)
                        acc1[i][u] += wv1 * vec[u + d];
                }
            }
        }

    // ---- write aws (bf16) + final out1 (flag dtype) ----
    const bool f32o = (*nf > NANTHRESH);
    bf16* awsb = aws + (long long)b * 1048576;
#pragma unroll
    for (int i = 0; i < 4; i++) {
        int n = n0 + i;
        bf16x4 o4;
#pragma unroll
        for (int u = 0; u < 4; u++) o4[u] = (bf16)acc1[i][u];
        *reinterpret_cast<bf16x4*>(&awsb[(long long)n * 1024 + m0]) = o4;
        long long fo = 2097152LL + (long long)b * 1048576 + (long long)n * 1024 + m0;
        if (f32o) {
            f32x4 of = {acc1[i][0], acc1[i][1], acc1[i][2], acc1[i][3]};
            *reinterpret_cast<f32x4*>(&((float*)dout)[fo]) = of;
        } else {
            *reinterpret_cast<bf16x4*>(&((bf16*)dout)[fo]) = o4;
        }
    }
}

// ---------------------------------------------------------------------------
// im2col: src [B][N][C] -> dst [B][N][C*9] (k = ci*9 + t)
// ---------------------------------------------------------------------------
__global__ __launch_bounds__(256) void k_im2col(
    const bf16* __restrict__ src, bf16* __restrict__ dst)
{
    const int blk = blockIdx.x;
    const int b = blk >> 10, n = blk & 1023;
    const int h = n >> 5, w = n & 31;
    const int ci = threadIdx.x;
    const bf16* sb = src + (long long)b * 262144;
    bf16* db = dst + ((long long)b * 1024 + n) * 2304 + ci * 9;
#pragma unroll
    for (int dh = 0; dh < 3; dh++)
#pragma unroll
        for (int dw_ = 0; dw_ < 3; dw_++) {
            int hh = h + dh - 1, ww = w + dw_ - 1;
            bf16 vv = (bf16)0.0f;
            if (hh >= 0 && hh < 32 && ww >= 0 && ww < 32)
                vv = sb[(hh * 32 + ww) * 256 + ci];
            db[dh * 3 + dw_] = vv;
        }
}

extern "C" void kernel_launch(void* const* d_in, const int* in_sizes, int n_in,
                              void* d_out, int out_size, void* d_ws, size_t ws_size,
                              hipStream_t stream)
{
    bf16* ws = (bf16*)d_ws;
    int* flagp = (int*)(ws + FLAG_ELOFF);

    bf16* cw      = ws + CW_OFF;
    bf16* cx      = ws + CX_OFF;
    bf16* dwq     = ws + DWQ_OFF;
    bf16* dwk     = ws + DWK_OFF;
    bf16* dwv     = ws + DWV_OFF;
    bf16* qT      = ws + QT_OFF;
    bf16* kT      = ws + KT_OFF;
    bf16* v       = ws + V_OFF;
    bf16* aws     = ws + AWS_OFF;
    bf16* att     = ws + ATT_OFF;
    bf16* outp    = ws + OUTP_OFF;
    bf16* colbuf  = ws + COL_OFF;

    bf16* c_qa_dw_w = cw + 0;      bf16* c_qa_dw_b = cw + 2304;
    bf16* c_qa_pw_w = cw + 2560;   bf16* c_qa_pw_b = cw + 68096;
    bf16* c_ka_dw_w = cw + 68352;  bf16* c_ka_dw_b = cw + 70656;
    bf16* c_ka_pw_w = cw + 70912;  bf16* c_ka_pw_b = cw + 333056;
    bf16* c_va_dw_w = cw + 334080; bf16* c_va_dw_b = cw + 336384;
    bf16* c_va_pw_w = cw + 336640; bf16* c_va_pw_b = cw + 402176;
    bf16* c_attn0   = cw + 402432;
    bf16* c_bn_g    = cw + 402576; bf16* c_bn_b = cw + 402580;
    bf16* c_bn_m    = cw + 402584; bf16* c_bn_v = cw + 402588;
    bf16* c_attn1   = cw + 402592;
    bf16* c_proj    = cw + 402640;

    // 0) dtype detect + normalize inputs to bf16
    k_zero<<<1, 64, 0, stream>>>(flagp);
    k_detect<<<64, 256, 0, stream>>>((const unsigned short*)d_in[0], flagp);
    SrcPtrs sp;
    for (int i = 0; i < 20; i++) sp.p[i] = d_in[i];
    k_convert<<<dim3(256, 20), 256, 0, stream>>>(sp, ws, flagp);

    // 1) depthwise convs (transposed outputs)
    k_dw<<<dim3(4, 16, 8), 256, 0, stream>>>(cx, c_qa_dw_w, c_qa_dw_b, c_ka_dw_w, c_ka_dw_b,
                                             c_va_dw_w, c_va_dw_b, dwq, dwk, dwv);
    // 2) pointwise GEMMs
    gemm_nt<<<dim3(4, 128, 1), 256, 0, stream>>>(dwq, c_qa_pw_w, c_qa_pw_b, qT,
        256, 256, 256, 256, 1, 0, 0, 0, 0, 0, 0, 1.0f, 2, flagp, 0);
    gemm_nt<<<dim3(16, 128, 1), 256, 0, stream>>>(dwk, c_ka_pw_w, c_ka_pw_b, kT,
        256, 256, 256, 1024, 1, 0, 0, 0, 0, 0, 0, 1.0f, 2, flagp, 0);
    gemm_nt<<<dim3(128, 4, 1), 256, 0, stream>>>(c_va_pw_w, dwv, c_va_pw_b, v,
        256, 256, 256, 8192, 1, 0, 0, 0, 0, 0, 0, 1.0f, 1, flagp, 0);
    // 3) attn = scale * q^T k, full batch: z = b*4+kk
    gemm_nt<<<dim3(16, 16, 32), 256, 0, stream>>>(qT, kT, nullptr, att,
        256, 256, 1024, 1024,
        4, 262144LL, 0LL, 1048576LL, 256LL, 4194304LL, 1048576LL,
        0.0625f, 0, flagp, 0);
    // 4+5) fused conv4->4 + BN + gating + conv4->1  -> aws + out1
    k_midconv<<<dim3(256, 8), 256, 0, stream>>>(att, c_attn0, c_bn_g, c_bn_b, c_bn_m, c_bn_v,
                                                c_attn1, aws, d_out, flagp);
    // 6) outp[b][n][c] = sum_m aws[b][n][m] * v[c][b*1024+m]
    gemm_nt<<<dim3(4, 16, 8), 256, 0, stream>>>(aws, v, nullptr, outp,
        1024, 1024, 8192, 256,
        1, 1048576LL, 0LL, 1024LL, 0LL, 262144LL, 0LL, 1.0f, 0, flagp, 0);
    // 7) proj conv: im2col + GEMM -> out0 (flag dtype)
    k_im2col<<<8192, 256, 0, stream>>>(outp, colbuf);
    gemm_nt<<<dim3(16, 4, 8), 256, 0, stream>>>(c_proj, colbuf, nullptr, d_out,
        2304, 2304, 2304, 1024,
        1, 0LL, 0LL, 2359296LL, 0LL, 262144LL, 0LL, 1.0f, 0, flagp, 1);
}